// Round 6
// baseline (568.388 us; speedup 1.0000x reference)
//
#include <hip/hip_runtime.h>

typedef __bf16 bf16;
typedef __bf16 bf16x4 __attribute__((ext_vector_type(4)));
typedef __bf16 bf16x8 __attribute__((ext_vector_type(8)));
typedef short  s16x4  __attribute__((ext_vector_type(4)));
typedef float  f32x4  __attribute__((ext_vector_type(4)));

#define NH   16
#define HD   64
#define DQ   1024
#define DKV  768
#define LQ   4096
#define LKV  1024
#define NB   2

__device__ __forceinline__ f32x4 mfma16(bf16x8 a, bf16x8 b, f32x4 c) {
    return __builtin_amdgcn_mfma_f32_16x16x32_bf16(a, b, c, 0, 0, 0);
}

// K=16 bf16 MFMA (v_mfma_f32_16x16x16_bf16, 2-VGPR A/B): B-operand layout
// (k=quad*4+j) matches the S^T C-layout directly.  Host pass gets a stub —
// __has_builtin on amdgcn builtins is false when clang targets x86.
#if defined(__HIP_DEVICE_COMPILE__)
#  if __has_builtin(__builtin_amdgcn_mfma_f32_16x16x16bf16_1k)
__device__ __forceinline__ f32x4 mfma16k16(bf16x4 a, bf16x4 b, f32x4 c) {
    union { bf16x4 h; s16x4 s; } ua, ub;
    ua.h = a; ub.h = b;
    return __builtin_amdgcn_mfma_f32_16x16x16bf16_1k(ua.s, ub.s, c, 0, 0, 0);
}
#  else
__device__ __forceinline__ f32x4 mfma16k16(bf16x4 a, bf16x4 b, f32x4 c) {
    f32x4 d;
    asm volatile("v_mfma_f32_16x16x16_bf16 %0, %1, %2, %3"
                 : "=v"(d) : "v"(a), "v"(b), "v"(c));
    return d;
}
#  endif
#else
__device__ __forceinline__ f32x4 mfma16k16(bf16x4 a, bf16x4 b, f32x4 c) { return c; }
#endif

// async global->LDS, 16B per lane; LDS dest wave-uniform base (HW adds lane*16)
#define GLDS16(g, l) __builtin_amdgcn_global_load_lds(                      \
    (const __attribute__((address_space(1))) void*)(g),                     \
    (__attribute__((address_space(3))) void*)(l), 16, 0, 0)

// ------- merged transposes: 4 weights f32 (K x 1024) -> bf16 (1024 x K) ------
__global__ __launch_bounds__(256) void transpose_all(
        const float* __restrict__ Wq, const float* __restrict__ Wk,
        const float* __restrict__ Wv, const float* __restrict__ Wo,
        bf16* __restrict__ Wq_t, bf16* __restrict__ Wk_t,
        bf16* __restrict__ Wv_t, bf16* __restrict__ Wo_t) {
    __shared__ float tile[32][33];
    const float* in; bf16* out; int K;
    switch (blockIdx.z) {
        case 0:  in = Wq; out = Wq_t; K = DQ;  break;
        case 1:  in = Wk; out = Wk_t; K = DKV; break;
        case 2:  in = Wv; out = Wv_t; K = DKV; break;
        default: in = Wo; out = Wo_t; K = DQ;  break;
    }
    int n0 = blockIdx.x * 32, k0 = blockIdx.y * 32;
    if (k0 >= K) return;
    int tx = threadIdx.x, ty = threadIdx.y;  // (32,8)
    for (int yy = 0; yy < 32; yy += 8)
        tile[ty + yy][tx] = in[(size_t)(k0 + ty + yy) * DQ + n0 + tx];
    __syncthreads();
    for (int yy = 0; yy < 32; yy += 8)
        out[(size_t)(n0 + ty + yy) * K + k0 + tx] = (bf16)tile[tx][ty + yy];
}

// ------- merged f32->bf16 convert (x then y), 8 elems/thread -----------------
__global__ __launch_bounds__(256) void cvt_all(const float* __restrict__ x,
                                               const float* __restrict__ y,
                                               bf16* __restrict__ xb,
                                               bf16* __restrict__ yb,
                                               int nx8, int ntot8) {
    int i = blockIdx.x * 256 + threadIdx.x;
    if (i >= ntot8) return;
    const float* in; bf16* out; int j;
    if (i < nx8) { in = x; out = xb; j = i; }
    else         { in = y; out = yb; j = i - nx8; }
    float4 a0 = ((const float4*)in)[(size_t)j * 2];
    float4 a1 = ((const float4*)in)[(size_t)j * 2 + 1];
    bf16x8 v = {(bf16)a0.x, (bf16)a0.y, (bf16)a0.z, (bf16)a0.w,
                (bf16)a1.x, (bf16)a1.y, (bf16)a1.z, (bf16)a1.w};
    ((bf16x8*)out)[j] = v;
}

// ------- 128x128-tile GEMM body: C = A(MxK,bf16) @ Bt(NxK,bf16)^T + bias -----
// MODE 0: C bf16 row-major. MODE 1: V-transposed bf16 vT[b,h,d,kv]. MODE 2: C f32.
template <int MODE>
__device__ __forceinline__ void gemm_body(const bf16* __restrict__ A,
                                          const bf16* __restrict__ Bt,
                                          const float* __restrict__ bias,
                                          void* __restrict__ Cv,
                                          int N, int K) {
    __shared__ bf16 As[128 * 32];
    __shared__ bf16 Bs[128 * 32];
    int tid  = threadIdx.x;
    int lane = tid & 63, w = tid >> 6;
    int quad = lane >> 4, l15 = lane & 15;
    int wm = (w >> 1) * 64, wn = (w & 1) * 64;
    int m0 = blockIdx.y * 128, n0 = blockIdx.x * 128;
    int srow = tid >> 2, scol = (tid & 3) * 8;
    const bf16* Ag = &A [(size_t)(m0 + srow) * K + scol];
    const bf16* Bg = &Bt[(size_t)(n0 + srow) * K + scol];
    bf16* Asw = As + w * 512;
    bf16* Bsw = Bs + w * 512;

    f32x4 acc[4][4] = {};

    for (int k0 = 0; k0 < K; k0 += 32) {
        GLDS16(Ag + k0,                  Asw);
        GLDS16(Ag + (size_t)64 * K + k0, Asw + 2048);
        GLDS16(Bg + k0,                  Bsw);
        GLDS16(Bg + (size_t)64 * K + k0, Bsw + 2048);
        __syncthreads();
        bf16x8 af[4], bfr[4];
#pragma unroll
        for (int i = 0; i < 4; i++)
            af[i] = *(const bf16x8*)&As[(size_t)(wm + i * 16 + l15) * 32 + quad * 8];
#pragma unroll
        for (int j = 0; j < 4; j++)
            bfr[j] = *(const bf16x8*)&Bs[(size_t)(wn + j * 16 + l15) * 32 + quad * 8];
#pragma unroll
        for (int i = 0; i < 4; i++)
#pragma unroll
            for (int j = 0; j < 4; j++)
                acc[i][j] = mfma16(af[i], bfr[j], acc[i][j]);
        __syncthreads();
    }

    bf16*  Cb = (bf16*)Cv;
    float* Cf = (float*)Cv;
#pragma unroll
    for (int i = 0; i < 4; i++)
#pragma unroll
        for (int j = 0; j < 4; j++) {
            int col = n0 + wn + j * 16 + l15;
            float bcol = bias[col];
            if (MODE == 1) {
                int rowb = m0 + wm + i * 16 + quad * 4;      // 4 consecutive kv
                int bb = rowb >> 10, kv = rowb & 1023;       // LKV = 1024
                int h = col >> 6, d = col & 63;
                bf16x4 val = {(bf16)(acc[i][j][0] + bcol), (bf16)(acc[i][j][1] + bcol),
                              (bf16)(acc[i][j][2] + bcol), (bf16)(acc[i][j][3] + bcol)};
                *(bf16x4*)&Cb[(((size_t)(bb * NH + h) * HD) + d) * LKV + kv] = val;
            } else {
#pragma unroll
                for (int r = 0; r < 4; r++) {
                    int row = m0 + wm + i * 16 + quad * 4 + r;
                    float v = acc[i][j][r] + bcol;
                    if (MODE == 2) Cf[(size_t)row * N + col] = v;
                    else           Cb[(size_t)row * N + col] = (bf16)v;
                }
            }
        }
}

__global__ __launch_bounds__(256) void gemm_q(const bf16* A, const bf16* Bt,
                                              const float* bias, void* Cv) {
    gemm_body<0>(A, Bt, bias, Cv, DQ, DQ);
}
__global__ __launch_bounds__(256) void gemm_o(const bf16* A, const bf16* Bt,
                                              const float* bias, void* Cv) {
    gemm_body<2>(A, Bt, bias, Cv, DQ, DQ);
}
__global__ __launch_bounds__(256) void gemm_kv(const bf16* yb,
                                               const bf16* Wk_t, const float* bk, bf16* kbuf,
                                               const bf16* Wv_t, const float* bv, bf16* vT) {
    if (blockIdx.z == 0) gemm_body<0>(yb, Wk_t, bk, kbuf, DQ, DKV);
    else                 gemm_body<1>(yb, Wv_t, bv, vT,   DQ, DKV);
}

// ------- merged RMSNorm (over 1024) + RoPE (head 64), in place on bf16 -------
__global__ __launch_bounds__(256) void rmsnorm_rope2(bf16* __restrict__ qb,
                                                     bf16* __restrict__ kb,
                                                     const float* __restrict__ gq,
                                                     const float* __restrict__ gk,
                                                     const float* __restrict__ xc,
                                                     const float* __restrict__ xs,
                                                     const float* __restrict__ yc,
                                                     const float* __restrict__ ys) {
    __shared__ float buf[1024];
    __shared__ float red[4];
    int row = blockIdx.x;
    bf16* t; const float *g, *cs, *sn;
    if (row < NB * LQ) {
        t = qb + (size_t)row * DQ; g = gq;
        cs = xc + (size_t)row * HD; sn = xs + (size_t)row * HD;
    } else {
        int r2 = row - NB * LQ;
        t = kb + (size_t)r2 * DQ; g = gk;
        cs = yc + (size_t)r2 * HD; sn = ys + (size_t)r2 * HD;
    }
    int tid = threadIdx.x;
    int c0 = tid * 4;
    bf16x4 v4 = *(const bf16x4*)&t[c0];
    float ss = 0.f;
#pragma unroll
    for (int j = 0; j < 4; j++) {
        float v = (float)v4[j];
        buf[c0 + j] = v;
        ss += v * v;
    }
#pragma unroll
    for (int off = 32; off >= 1; off >>= 1) ss += __shfl_xor(ss, off, 64);
    if ((tid & 63) == 0) red[tid >> 6] = ss;
    __syncthreads();
    float tot = red[0] + red[1] + red[2] + red[3];
    float rms = rsqrtf(tot * (1.0f / 1024.0f) + 1e-6f);
    bf16x4 o4;
#pragma unroll
    for (int j = 0; j < 4; j++) {
        int c = c0 + j;
        int d = c & 63;
        float tv = buf[c] * rms * g[c];
        int   p  = (d < 32) ? c + 32 : c - 32;
        float pv = buf[p] * rms * g[p];
        float sgn = (d < 32) ? -1.f : 1.f;
        o4[j] = (bf16)(tv * cs[d] + sgn * pv * sn[d]);
    }
    *(bf16x4*)&t[c0] = o4;
}

// ------- flash attention v3: S^T form, no LDS, no barriers -------------------
// block = (b,h,64 q rows), wave w owns q rows w*16..+15.
// S^T = K·Q^T via 16x16x32; C-layout (kv=quad*4+r, q=l15) feeds PV directly
// as B-operand of 16x16x16: O^T = V^T·P^T.  Scalar m,l per lane (q=l15).
__global__ __launch_bounds__(256) void attn_kern(const bf16* __restrict__ q,
                                                 const bf16* __restrict__ k,
                                                 const bf16* __restrict__ vT,
                                                 bf16* __restrict__ o) {
    int tid = threadIdx.x, w = tid >> 6, lane = tid & 63;
    int quad = lane >> 4, l15 = lane & 15;
    int b = blockIdx.z, h = blockIdx.y, qt = blockIdx.x;
    int qrow0 = qt * 64 + w * 16;

    const size_t qbase = ((size_t)(b * LQ) + qrow0) * DQ + h * HD;
    bf16x8 qf0 = *(const bf16x8*)&q[qbase + (size_t)l15 * DQ + quad * 8];
    bf16x8 qf1 = *(const bf16x8*)&q[qbase + (size_t)l15 * DQ + 32 + quad * 8];
#pragma unroll
    for (int e = 0; e < 8; e++) {           // fold 1/8 scale; 2^-3 exact in bf16
        qf0[e] = (bf16)((float)qf0[e] * 0.125f);
        qf1[e] = (bf16)((float)qf1[e] * 0.125f);
    }

    const bf16* kp = &k[(size_t)(b * LKV) * DQ + h * HD + (size_t)l15 * DQ];
    const size_t vbase = (size_t)((b * NH + h) * HD) * LKV;

    f32x4 O[4] = {};
    float m_run = -1e30f, l_run = 0.f;

    bf16x8 kf[4][2];
#pragma unroll
    for (int t = 0; t < 4; t++) {
        kf[t][0] = *(const bf16x8*)&kp[(size_t)(t * 16) * DQ + quad * 8];
        kf[t][1] = *(const bf16x8*)&kp[(size_t)(t * 16) * DQ + 32 + quad * 8];
    }
    f32x4 S[4];
#pragma unroll
    for (int t = 0; t < 4; t++) {
        f32x4 z = {};
        z = mfma16(kf[t][0], qf0, z);
        S[t] = mfma16(kf[t][1], qf1, z);
    }

    for (int kv0 = 0; kv0 < LKV; kv0 += 64) {
        int kn = (kv0 + 64) & (LKV - 1);    // wraps to 0 last iter (result unused)
        // prefetch next K chunk (consumed after PV)
#pragma unroll
        for (int t = 0; t < 4; t++) {
            kf[t][0] = *(const bf16x8*)&kp[(size_t)(kn + t * 16) * DQ + quad * 8];
            kf[t][1] = *(const bf16x8*)&kp[(size_t)(kn + t * 16) * DQ + 32 + quad * 8];
        }
        // V fragments for this chunk (issued before the softmax chain)
        bf16x4 vf[4][4];
#pragma unroll
        for (int seg = 0; seg < 4; seg++)
#pragma unroll
            for (int td = 0; td < 4; td++)
                vf[seg][td] = *(const bf16x4*)
                    &vT[vbase + (size_t)(td * 16 + l15) * LKV + kv0 + seg * 16 + quad * 4];
        // online softmax: scalar state per lane (q = l15)
        float mx = -1e30f;
#pragma unroll
        for (int t = 0; t < 4; t++)
#pragma unroll
            for (int r = 0; r < 4; r++) mx = fmaxf(mx, S[t][r]);
        mx = fmaxf(mx, __shfl_xor(mx, 16, 64));
        mx = fmaxf(mx, __shfl_xor(mx, 32, 64));
        float mn = fmaxf(m_run, mx);
        float alpha = __expf(m_run - mn);
        m_run = mn;
        float rs = 0.f;
        bf16x4 pb[4];
#pragma unroll
        for (int t = 0; t < 4; t++) {
            float p0 = __expf(S[t][0] - mn), p1 = __expf(S[t][1] - mn);
            float p2 = __expf(S[t][2] - mn), p3 = __expf(S[t][3] - mn);
            rs += (p0 + p1) + (p2 + p3);
            pb[t] = bf16x4{(bf16)p0, (bf16)p1, (bf16)p2, (bf16)p3};
        }
        rs += __shfl_xor(rs, 16, 64);
        rs += __shfl_xor(rs, 32, 64);
        l_run = l_run * alpha + rs;
#pragma unroll
        for (int td = 0; td < 4; td++)
#pragma unroll
            for (int r = 0; r < 4; r++) O[td][r] *= alpha;
        // PV: O^T[d][q] += V^T·P^T, contraction kv=16 per MFMA
#pragma unroll
        for (int seg = 0; seg < 4; seg++)
#pragma unroll
            for (int td = 0; td < 4; td++)
                O[td] = mfma16k16(vf[seg][td], pb[seg], O[td]);
        // S for next chunk from prefetched K
#pragma unroll
        for (int t = 0; t < 4; t++) {
            f32x4 z = {};
            z = mfma16(kf[t][0], qf0, z);
            S[t] = mfma16(kf[t][1], qf1, z);
        }
    }

    float inv = 1.0f / l_run;
    size_t orow = ((size_t)(b * LQ) + qrow0 + l15) * DQ + h * HD;
#pragma unroll
    for (int td = 0; td < 4; td++) {
        bf16x4 ov = {(bf16)(O[td][0] * inv), (bf16)(O[td][1] * inv),
                     (bf16)(O[td][2] * inv), (bf16)(O[td][3] * inv)};
        *(bf16x4*)&o[orow + td * 16 + quad * 4] = ov;
    }
}

// ---------------------------------------------------------------------------
extern "C" void kernel_launch(void* const* d_in, const int* in_sizes, int n_in,
                              void* d_out, int out_size, void* d_ws, size_t ws_size,
                              hipStream_t stream) {
    const float* x     = (const float*)d_in[0];
    const float* y     = (const float*)d_in[1];
    const float* x_cos = (const float*)d_in[2];
    const float* x_sin = (const float*)d_in[3];
    const float* y_cos = (const float*)d_in[4];
    const float* y_sin = (const float*)d_in[5];
    const float* Wq    = (const float*)d_in[6];
    const float* bq    = (const float*)d_in[7];
    const float* Wk    = (const float*)d_in[8];
    const float* bk    = (const float*)d_in[9];
    const float* Wv    = (const float*)d_in[10];
    const float* bv    = (const float*)d_in[11];
    const float* Wo    = (const float*)d_in[12];
    const float* bo    = (const float*)d_in[13];
    const float* gq    = (const float*)d_in[14];
    const float* gk    = (const float*)d_in[15];

    char* ws = (char*)d_ws;
    bf16* Wq_t = (bf16*)ws;  ws += (size_t)DQ * DQ * 2;
    bf16* Wk_t = (bf16*)ws;  ws += (size_t)DQ * DKV * 2;
    bf16* Wv_t = (bf16*)ws;  ws += (size_t)DQ * DKV * 2;
    bf16* Wo_t = (bf16*)ws;  ws += (size_t)DQ * DQ * 2;
    bf16* qbuf = (bf16*)ws;  ws += (size_t)NB * LQ * DQ * 2;
    bf16* kbuf = (bf16*)ws;  ws += (size_t)NB * LKV * DQ * 2;
    bf16* vT   = (bf16*)ws;  ws += (size_t)NB * NH * HD * LKV * 2;
    bf16* aout = (bf16*)ws;  ws += (size_t)NB * LQ * DQ * 2;
    bf16* yb   = (bf16*)ws;  ws += (size_t)NB * LKV * DKV * 2;
    bf16* xb   = aout;  // alias: xb dead (last read = Q-proj) before attn writes aout

    transpose_all<<<dim3(32, 32, 4), dim3(32, 8), 0, stream>>>(
        Wq, Wk, Wv, Wo, Wq_t, Wk_t, Wv_t, Wo_t);

    int nx8 = NB * LQ * DQ / 8, ny8 = NB * LKV * DKV / 8;
    int ntot8 = nx8 + ny8;
    cvt_all<<<(ntot8 + 255) / 256, 256, 0, stream>>>(x, y, xb, yb, nx8, ntot8);

    gemm_q<<<dim3(DQ / 128, NB * LQ / 128), 256, 0, stream>>>(xb, Wq_t, bq, qbuf);
    gemm_kv<<<dim3(DQ / 128, NB * LKV / 128, 2), 256, 0, stream>>>(
        yb, Wk_t, bk, kbuf, Wv_t, bv, vT);

    rmsnorm_rope2<<<NB * (LQ + LKV), 256, 0, stream>>>(
        qbuf, kbuf, gq, gk, x_cos, x_sin, y_cos, y_sin);

    attn_kern<<<dim3(LQ / 64, NH, NB), 256, 0, stream>>>(qbuf, kbuf, vT, aout);

    gemm_o<<<dim3(DQ / 128, NB * LQ / 128), 256, 0, stream>>>(aout, Wo_t, bo, d_out);
}

// Round 7
// 346.997 us; speedup vs baseline: 1.6380x; 1.6380x over previous
//
#include <hip/hip_runtime.h>

typedef __bf16 bf16;
typedef __bf16 bf16x4 __attribute__((ext_vector_type(4)));
typedef __bf16 bf16x8 __attribute__((ext_vector_type(8)));
typedef float  f32x4  __attribute__((ext_vector_type(4)));

#define NH   16
#define HD   64
#define DQ   1024
#define DKV  768
#define LQ   4096
#define LKV  1024
#define NB   2

__device__ __forceinline__ f32x4 mfma16(bf16x8 a, bf16x8 b, f32x4 c) {
    return __builtin_amdgcn_mfma_f32_16x16x32_bf16(a, b, c, 0, 0, 0);
}

// async global->LDS, 16B per lane; LDS dest wave-uniform base (HW adds lane*16)
#define GLDS16(g, l) __builtin_amdgcn_global_load_lds(                      \
    (const __attribute__((address_space(1))) void*)(g),                     \
    (__attribute__((address_space(3))) void*)(l), 16, 0, 0)

// ------- merged transposes: 4 weights f32 (K x 1024) -> bf16 (1024 x K) ------
__global__ __launch_bounds__(256) void transpose_all(
        const float* __restrict__ Wq, const float* __restrict__ Wk,
        const float* __restrict__ Wv, const float* __restrict__ Wo,
        bf16* __restrict__ Wq_t, bf16* __restrict__ Wk_t,
        bf16* __restrict__ Wv_t, bf16* __restrict__ Wo_t) {
    __shared__ float tile[32][33];
    const float* in; bf16* out; int K;
    switch (blockIdx.z) {
        case 0:  in = Wq; out = Wq_t; K = DQ;  break;
        case 1:  in = Wk; out = Wk_t; K = DKV; break;
        case 2:  in = Wv; out = Wv_t; K = DKV; break;
        default: in = Wo; out = Wo_t; K = DQ;  break;
    }
    int n0 = blockIdx.x * 32, k0 = blockIdx.y * 32;
    if (k0 >= K) return;
    int tx = threadIdx.x, ty = threadIdx.y;  // (32,8)
    for (int yy = 0; yy < 32; yy += 8)
        tile[ty + yy][tx] = in[(size_t)(k0 + ty + yy) * DQ + n0 + tx];
    __syncthreads();
    for (int yy = 0; yy < 32; yy += 8)
        out[(size_t)(n0 + ty + yy) * K + k0 + tx] = (bf16)tile[tx][ty + yy];
}

// ------- merged f32->bf16 convert (x then y), 8 elems/thread -----------------
__global__ __launch_bounds__(256) void cvt_all(const float* __restrict__ x,
                                               const float* __restrict__ y,
                                               bf16* __restrict__ xb,
                                               bf16* __restrict__ yb,
                                               int nx8, int ntot8) {
    int i = blockIdx.x * 256 + threadIdx.x;
    if (i >= ntot8) return;
    const float* in; bf16* out; int j;
    if (i < nx8) { in = x; out = xb; j = i; }
    else         { in = y; out = yb; j = i - nx8; }
    float4 a0 = ((const float4*)in)[(size_t)j * 2];
    float4 a1 = ((const float4*)in)[(size_t)j * 2 + 1];
    bf16x8 v = {(bf16)a0.x, (bf16)a0.y, (bf16)a0.z, (bf16)a0.w,
                (bf16)a1.x, (bf16)a1.y, (bf16)a1.z, (bf16)a1.w};
    ((bf16x8*)out)[j] = v;
}

// ------- 128x128-tile GEMM body: C = A(MxK,bf16) @ Bt(NxK,bf16)^T + bias -----
// MODE 0: C bf16 row-major. MODE 1: V-transposed bf16 vT[b,h,d,kv]. MODE 2: C f32.
template <int MODE>
__device__ __forceinline__ void gemm_body(const bf16* __restrict__ A,
                                          const bf16* __restrict__ Bt,
                                          const float* __restrict__ bias,
                                          void* __restrict__ Cv,
                                          int N, int K) {
    __shared__ bf16 As[128 * 32];
    __shared__ bf16 Bs[128 * 32];
    int tid  = threadIdx.x;
    int lane = tid & 63, w = tid >> 6;
    int quad = lane >> 4, l15 = lane & 15;
    int wm = (w >> 1) * 64, wn = (w & 1) * 64;
    int m0 = blockIdx.y * 128, n0 = blockIdx.x * 128;
    int srow = tid >> 2, scol = (tid & 3) * 8;
    const bf16* Ag = &A [(size_t)(m0 + srow) * K + scol];
    const bf16* Bg = &Bt[(size_t)(n0 + srow) * K + scol];
    bf16* Asw = As + w * 512;
    bf16* Bsw = Bs + w * 512;

    f32x4 acc[4][4] = {};

    for (int k0 = 0; k0 < K; k0 += 32) {
        GLDS16(Ag + k0,                  Asw);
        GLDS16(Ag + (size_t)64 * K + k0, Asw + 2048);
        GLDS16(Bg + k0,                  Bsw);
        GLDS16(Bg + (size_t)64 * K + k0, Bsw + 2048);
        __syncthreads();
        bf16x8 af[4], bfr[4];
#pragma unroll
        for (int i = 0; i < 4; i++)
            af[i] = *(const bf16x8*)&As[(size_t)(wm + i * 16 + l15) * 32 + quad * 8];
#pragma unroll
        for (int j = 0; j < 4; j++)
            bfr[j] = *(const bf16x8*)&Bs[(size_t)(wn + j * 16 + l15) * 32 + quad * 8];
#pragma unroll
        for (int i = 0; i < 4; i++)
#pragma unroll
            for (int j = 0; j < 4; j++)
                acc[i][j] = mfma16(af[i], bfr[j], acc[i][j]);
        __syncthreads();
    }

    bf16*  Cb = (bf16*)Cv;
    float* Cf = (float*)Cv;
#pragma unroll
    for (int i = 0; i < 4; i++)
#pragma unroll
        for (int j = 0; j < 4; j++) {
            int col = n0 + wn + j * 16 + l15;
            float bcol = bias[col];
            if (MODE == 1) {
                int rowb = m0 + wm + i * 16 + quad * 4;      // 4 consecutive kv
                int bb = rowb >> 10, kv = rowb & 1023;       // LKV = 1024
                int h = col >> 6, d = col & 63;
                bf16x4 val = {(bf16)(acc[i][j][0] + bcol), (bf16)(acc[i][j][1] + bcol),
                              (bf16)(acc[i][j][2] + bcol), (bf16)(acc[i][j][3] + bcol)};
                *(bf16x4*)&Cb[(((size_t)(bb * NH + h) * HD) + d) * LKV + kv] = val;
            } else {
#pragma unroll
                for (int r = 0; r < 4; r++) {
                    int row = m0 + wm + i * 16 + quad * 4 + r;
                    float v = acc[i][j][r] + bcol;
                    if (MODE == 2) Cf[(size_t)row * N + col] = v;
                    else           Cb[(size_t)row * N + col] = (bf16)v;
                }
            }
        }
}

__global__ __launch_bounds__(256) void gemm_q(const bf16* A, const bf16* Bt,
                                              const float* bias, void* Cv) {
    gemm_body<0>(A, Bt, bias, Cv, DQ, DQ);
}
__global__ __launch_bounds__(256) void gemm_o(const bf16* A, const bf16* Bt,
                                              const float* bias, void* Cv) {
    gemm_body<2>(A, Bt, bias, Cv, DQ, DQ);
}
__global__ __launch_bounds__(256) void gemm_kv(const bf16* yb,
                                               const bf16* Wk_t, const float* bk, bf16* kbuf,
                                               const bf16* Wv_t, const float* bv, bf16* vT) {
    if (blockIdx.z == 0) gemm_body<0>(yb, Wk_t, bk, kbuf, DQ, DKV);
    else                 gemm_body<1>(yb, Wv_t, bv, vT,   DQ, DKV);
}

// ------- merged RMSNorm (over 1024) + RoPE (head 64), in place on bf16 -------
__global__ __launch_bounds__(256) void rmsnorm_rope2(bf16* __restrict__ qb,
                                                     bf16* __restrict__ kb,
                                                     const float* __restrict__ gq,
                                                     const float* __restrict__ gk,
                                                     const float* __restrict__ xc,
                                                     const float* __restrict__ xs,
                                                     const float* __restrict__ yc,
                                                     const float* __restrict__ ys) {
    __shared__ float buf[1024];
    __shared__ float red[4];
    int row = blockIdx.x;
    bf16* t; const float *g, *cs, *sn;
    if (row < NB * LQ) {
        t = qb + (size_t)row * DQ; g = gq;
        cs = xc + (size_t)row * HD; sn = xs + (size_t)row * HD;
    } else {
        int r2 = row - NB * LQ;
        t = kb + (size_t)r2 * DQ; g = gk;
        cs = yc + (size_t)r2 * HD; sn = ys + (size_t)r2 * HD;
    }
    int tid = threadIdx.x;
    int c0 = tid * 4;
    bf16x4 v4 = *(const bf16x4*)&t[c0];
    float ss = 0.f;
#pragma unroll
    for (int j = 0; j < 4; j++) {
        float v = (float)v4[j];
        buf[c0 + j] = v;
        ss += v * v;
    }
#pragma unroll
    for (int off = 32; off >= 1; off >>= 1) ss += __shfl_xor(ss, off, 64);
    if ((tid & 63) == 0) red[tid >> 6] = ss;
    __syncthreads();
    float tot = red[0] + red[1] + red[2] + red[3];
    float rms = rsqrtf(tot * (1.0f / 1024.0f) + 1e-6f);
    bf16x4 o4;
#pragma unroll
    for (int j = 0; j < 4; j++) {
        int c = c0 + j;
        int d = c & 63;
        float tv = buf[c] * rms * g[c];
        int   p  = (d < 32) ? c + 32 : c - 32;
        float pv = buf[p] * rms * g[p];
        float sgn = (d < 32) ? -1.f : 1.f;
        o4[j] = (bf16)(tv * cs[d] + sgn * pv * sn[d]);
    }
    *(bf16x4*)&t[c0] = o4;
}

// ------- flash attention v4: S^T QK + K=32 PV (LDS P-roundtrip), 32 q/wave ---
// block = (b,h,128 q rows), wave w owns q rows {w*16..+15} and {64+w*16..+15}.
// S^T = K·Q^T (16x16x32). C-layout (kv=quad*4+r, q=l15) → pbuf[q][kv] → read
// back as B-operand (k=quad*8+j) for O^T = V^T·P^T (16x16x32, A=V^T).
// O^T C-layout: row=d=quad*4+r, col=q=l15 → alpha/l are per-lane scalars.
__global__ __launch_bounds__(256) void attn_kern(const bf16* __restrict__ q,
                                                 const bf16* __restrict__ k,
                                                 const bf16* __restrict__ vT,
                                                 bf16* __restrict__ o) {
    __shared__ bf16 pbuf[4][2][16][72];     // [wave][tile][q][kv] (+pad)
    int tid = threadIdx.x, w = tid >> 6, lane = tid & 63;
    int quad = lane >> 4, l15 = lane & 15;
    int b = blockIdx.z, h = blockIdx.y, qt = blockIdx.x;
    int qrow0 = qt * 128 + w * 16;

    bf16x8 qf[2][2];
#pragma unroll
    for (int tl = 0; tl < 2; tl++) {
        size_t qb = ((size_t)(b * LQ) + qrow0 + tl * 64 + l15) * DQ + h * HD;
        qf[tl][0] = *(const bf16x8*)&q[qb + quad * 8];
        qf[tl][1] = *(const bf16x8*)&q[qb + 32 + quad * 8];
#pragma unroll
        for (int e = 0; e < 8; e++) {       // fold 1/8 scale; 2^-3 exact in bf16
            qf[tl][0][e] = (bf16)((float)qf[tl][0][e] * 0.125f);
            qf[tl][1][e] = (bf16)((float)qf[tl][1][e] * 0.125f);
        }
    }

    const bf16* kp = &k[(size_t)(b * LKV) * DQ + h * HD + (size_t)l15 * DQ];
    const size_t vbase = (size_t)((b * NH + h) * HD) * LKV;

    f32x4 O[2][4] = {};
    float m_run[2] = {-1e30f, -1e30f}, l_run[2] = {0.f, 0.f};

    bf16x8 kf[4][2];
#pragma unroll
    for (int t = 0; t < 4; t++) {
        kf[t][0] = *(const bf16x8*)&kp[(size_t)(t * 16) * DQ + quad * 8];
        kf[t][1] = *(const bf16x8*)&kp[(size_t)(t * 16) * DQ + 32 + quad * 8];
    }
    f32x4 S[2][4];
#pragma unroll
    for (int tl = 0; tl < 2; tl++)
#pragma unroll
        for (int t = 0; t < 4; t++) {
            f32x4 z = {};
            z = mfma16(kf[t][0], qf[tl][0], z);
            S[tl][t] = mfma16(kf[t][1], qf[tl][1], z);
        }

    for (int kv0 = 0; kv0 < LKV; kv0 += 64) {
        int kn = (kv0 + 64) & (LKV - 1);    // wraps last iter (result unused)
        // prefetch next K chunk (consumed by S-next at loop bottom)
#pragma unroll
        for (int t = 0; t < 4; t++) {
            kf[t][0] = *(const bf16x8*)&kp[(size_t)(kn + t * 16) * DQ + quad * 8];
            kf[t][1] = *(const bf16x8*)&kp[(size_t)(kn + t * 16) * DQ + 32 + quad * 8];
        }
        // V fragments for this chunk — shared by both q-row tiles
        bf16x8 vf[4][2];
#pragma unroll
        for (int td = 0; td < 4; td++) {
            const bf16* vr = &vT[vbase + (size_t)(td * 16 + l15) * LKV + kv0];
            vf[td][0] = *(const bf16x8*)&vr[quad * 8];
            vf[td][1] = *(const bf16x8*)&vr[32 + quad * 8];
        }
        // online softmax per tile: scalar state per lane (q = l15)
#pragma unroll
        for (int tl = 0; tl < 2; tl++) {
            float mx = -1e30f;
#pragma unroll
            for (int t = 0; t < 4; t++)
#pragma unroll
                for (int r = 0; r < 4; r++) mx = fmaxf(mx, S[tl][t][r]);
            mx = fmaxf(mx, __shfl_xor(mx, 16, 64));
            mx = fmaxf(mx, __shfl_xor(mx, 32, 64));
            float mn = fmaxf(m_run[tl], mx);
            float alpha = __expf(m_run[tl] - mn);
            m_run[tl] = mn;
            float rs = 0.f;
#pragma unroll
            for (int t = 0; t < 4; t++) {
                float p0 = __expf(S[tl][t][0] - mn), p1 = __expf(S[tl][t][1] - mn);
                float p2 = __expf(S[tl][t][2] - mn), p3 = __expf(S[tl][t][3] - mn);
                rs += (p0 + p1) + (p2 + p3);
                bf16x4 pb4 = {(bf16)p0, (bf16)p1, (bf16)p2, (bf16)p3};
                *(bf16x4*)&pbuf[w][tl][l15][t * 16 + quad * 4] = pb4;
            }
            rs += __shfl_xor(rs, 16, 64);
            rs += __shfl_xor(rs, 32, 64);
            l_run[tl] = l_run[tl] * alpha + rs;
#pragma unroll
            for (int td = 0; td < 4; td++)
#pragma unroll
                for (int r = 0; r < 4; r++) O[tl][td][r] *= alpha;
        }
        asm volatile("s_waitcnt lgkmcnt(0)" ::: "memory");  // wave-local RAW on pbuf
        // PV: O^T += V^T·P^T (K=32), P read back in B-layout
#pragma unroll
        for (int tl = 0; tl < 2; tl++) {
            bf16x8 pf0 = *(const bf16x8*)&pbuf[w][tl][l15][quad * 8];
            bf16x8 pf1 = *(const bf16x8*)&pbuf[w][tl][l15][32 + quad * 8];
#pragma unroll
            for (int td = 0; td < 4; td++) {
                O[tl][td] = mfma16(vf[td][0], pf0, O[tl][td]);
                O[tl][td] = mfma16(vf[td][1], pf1, O[tl][td]);
            }
        }
        // S for next chunk from prefetched K
#pragma unroll
        for (int tl = 0; tl < 2; tl++)
#pragma unroll
            for (int t = 0; t < 4; t++) {
                f32x4 z = {};
                z = mfma16(kf[t][0], qf[tl][0], z);
                S[tl][t] = mfma16(kf[t][1], qf[tl][1], z);
            }
    }

#pragma unroll
    for (int tl = 0; tl < 2; tl++) {
        float inv = 1.0f / l_run[tl];
        size_t orow = ((size_t)(b * LQ) + qrow0 + tl * 64 + l15) * DQ + h * HD;
#pragma unroll
        for (int td = 0; td < 4; td++) {
            bf16x4 ov = {(bf16)(O[tl][td][0] * inv), (bf16)(O[tl][td][1] * inv),
                         (bf16)(O[tl][td][2] * inv), (bf16)(O[tl][td][3] * inv)};
            *(bf16x4*)&o[orow + td * 16 + quad * 4] = ov;
        }
    }
}

// ---------------------------------------------------------------------------
extern "C" void kernel_launch(void* const* d_in, const int* in_sizes, int n_in,
                              void* d_out, int out_size, void* d_ws, size_t ws_size,
                              hipStream_t stream) {
    const float* x     = (const float*)d_in[0];
    const float* y     = (const float*)d_in[1];
    const float* x_cos = (const float*)d_in[2];
    const float* x_sin = (const float*)d_in[3];
    const float* y_cos = (const float*)d_in[4];
    const float* y_sin = (const float*)d_in[5];
    const float* Wq    = (const float*)d_in[6];
    const float* bq    = (const float*)d_in[7];
    const float* Wk    = (const float*)d_in[8];
    const float* bk    = (const float*)d_in[9];
    const float* Wv    = (const float*)d_in[10];
    const float* bv    = (const float*)d_in[11];
    const float* Wo    = (const float*)d_in[12];
    const float* bo    = (const float*)d_in[13];
    const float* gq    = (const float*)d_in[14];
    const float* gk    = (const float*)d_in[15];

    char* ws = (char*)d_ws;
    bf16* Wq_t = (bf16*)ws;  ws += (size_t)DQ * DQ * 2;
    bf16* Wk_t = (bf16*)ws;  ws += (size_t)DQ * DKV * 2;
    bf16* Wv_t = (bf16*)ws;  ws += (size_t)DQ * DKV * 2;
    bf16* Wo_t = (bf16*)ws;  ws += (size_t)DQ * DQ * 2;
    bf16* qbuf = (bf16*)ws;  ws += (size_t)NB * LQ * DQ * 2;
    bf16* kbuf = (bf16*)ws;  ws += (size_t)NB * LKV * DQ * 2;
    bf16* vT   = (bf16*)ws;  ws += (size_t)NB * NH * HD * LKV * 2;
    bf16* aout = (bf16*)ws;  ws += (size_t)NB * LQ * DQ * 2;
    bf16* yb   = (bf16*)ws;  ws += (size_t)NB * LKV * DKV * 2;
    bf16* xb   = aout;  // alias: xb dead (last read = Q-proj) before attn writes aout

    transpose_all<<<dim3(32, 32, 4), dim3(32, 8), 0, stream>>>(
        Wq, Wk, Wv, Wo, Wq_t, Wk_t, Wv_t, Wo_t);

    int nx8 = NB * LQ * DQ / 8, ny8 = NB * LKV * DKV / 8;
    int ntot8 = nx8 + ny8;
    cvt_all<<<(ntot8 + 255) / 256, 256, 0, stream>>>(x, y, xb, yb, nx8, ntot8);

    gemm_q<<<dim3(DQ / 128, NB * LQ / 128), 256, 0, stream>>>(xb, Wq_t, bq, qbuf);
    gemm_kv<<<dim3(DQ / 128, NB * LKV / 128, 2), 256, 0, stream>>>(
        yb, Wk_t, bk, kbuf, Wv_t, bv, vT);

    rmsnorm_rope2<<<NB * (LQ + LKV), 256, 0, stream>>>(
        qbuf, kbuf, gq, gk, x_cos, x_sin, y_cos, y_sin);

    attn_kern<<<dim3(LQ / 128, NH, NB), 256, 0, stream>>>(qbuf, kbuf, vT, aout);

    gemm_o<<<dim3(DQ / 128, NB * LQ / 128), 256, 0, stream>>>(aout, Wo_t, bo, d_out);
}

// Round 8
// 298.533 us; speedup vs baseline: 1.9039x; 1.1623x over previous
//
#include <hip/hip_runtime.h>

typedef __bf16 bf16;
typedef __bf16 bf16x4 __attribute__((ext_vector_type(4)));
typedef __bf16 bf16x8 __attribute__((ext_vector_type(8)));
typedef float  f32x4  __attribute__((ext_vector_type(4)));

#define NH   16
#define HD   64
#define DQ   1024
#define DKV  768
#define LQ   4096
#define LKV  1024
#define NB   2

__device__ __forceinline__ f32x4 mfma16(bf16x8 a, bf16x8 b, f32x4 c) {
    return __builtin_amdgcn_mfma_f32_16x16x32_bf16(a, b, c, 0, 0, 0);
}

// async global->LDS, 16B per lane; LDS dest wave-uniform base (HW adds lane*16)
#define GLDS16(g, l) __builtin_amdgcn_global_load_lds(                      \
    (const __attribute__((address_space(1))) void*)(g),                     \
    (__attribute__((address_space(3))) void*)(l), 16, 0, 0)

// ------- prep: 4 weight transposes (f32 KxN -> bf16 NxK) + x/y f32->bf16 -----
__global__ __launch_bounds__(256) void prep(
        const float* __restrict__ Wq, const float* __restrict__ Wk,
        const float* __restrict__ Wv, const float* __restrict__ Wo,
        bf16* __restrict__ Wq_t, bf16* __restrict__ Wk_t,
        bf16* __restrict__ Wv_t, bf16* __restrict__ Wo_t,
        const float* __restrict__ x, const float* __restrict__ y,
        bf16* __restrict__ xb, bf16* __restrict__ yb,
        int nx8, int ntot8) {
    if (blockIdx.z < 4) {
        __shared__ float tile[32][33];
        const float* in; bf16* out; int K;
        switch (blockIdx.z) {
            case 0:  in = Wq; out = Wq_t; K = DQ;  break;
            case 1:  in = Wk; out = Wk_t; K = DKV; break;
            case 2:  in = Wv; out = Wv_t; K = DKV; break;
            default: in = Wo; out = Wo_t; K = DQ;  break;
        }
        int n0 = blockIdx.x * 32, k0 = blockIdx.y * 32;
        if (k0 >= K) return;
        int tx = threadIdx.x, ty = threadIdx.y;  // (32,8)
        for (int yy = 0; yy < 32; yy += 8)
            tile[ty + yy][tx] = in[(size_t)(k0 + ty + yy) * DQ + n0 + tx];
        __syncthreads();
        for (int yy = 0; yy < 32; yy += 8)
            out[(size_t)(n0 + ty + yy) * K + k0 + tx] = (bf16)tile[tx][ty + yy];
    } else {
        int tid = threadIdx.y * 32 + threadIdx.x;
        int flat = (blockIdx.y * 32 + blockIdx.x) * 256 + tid;  // 0..262143
        for (int i = flat; i < ntot8; i += 32 * 32 * 256) {
            const float* in; bf16* out; int j;
            if (i < nx8) { in = x; out = xb; j = i; }
            else         { in = y; out = yb; j = i - nx8; }
            float4 a0 = ((const float4*)in)[(size_t)j * 2];
            float4 a1 = ((const float4*)in)[(size_t)j * 2 + 1];
            bf16x8 v = {(bf16)a0.x, (bf16)a0.y, (bf16)a0.z, (bf16)a0.w,
                        (bf16)a1.x, (bf16)a1.y, (bf16)a1.z, (bf16)a1.w};
            ((bf16x8*)out)[j] = v;
        }
    }
}

// ------- 128x128-tile GEMM body: C = A(MxK,bf16) @ Bt(NxK,bf16)^T + bias -----
// MODE 0: C bf16 row-major. MODE 1: V-transposed bf16 vT[b,h,d,kv]. MODE 2: C f32.
template <int MODE>
__device__ __forceinline__ void gemm_body(const bf16* __restrict__ A,
                                          const bf16* __restrict__ Bt,
                                          const float* __restrict__ bias,
                                          void* __restrict__ Cv,
                                          int N, int K, int m0) {
    __shared__ bf16 As[128 * 32];
    __shared__ bf16 Bs[128 * 32];
    int tid  = threadIdx.x;
    int lane = tid & 63, w = tid >> 6;
    int quad = lane >> 4, l15 = lane & 15;
    int wm = (w >> 1) * 64, wn = (w & 1) * 64;
    int n0 = blockIdx.x * 128;
    int srow = tid >> 2, scol = (tid & 3) * 8;
    const bf16* Ag = &A [(size_t)(m0 + srow) * K + scol];
    const bf16* Bg = &Bt[(size_t)(n0 + srow) * K + scol];
    bf16* Asw = As + w * 512;
    bf16* Bsw = Bs + w * 512;

    f32x4 acc[4][4] = {};

    for (int k0 = 0; k0 < K; k0 += 32) {
        GLDS16(Ag + k0,                  Asw);
        GLDS16(Ag + (size_t)64 * K + k0, Asw + 2048);
        GLDS16(Bg + k0,                  Bsw);
        GLDS16(Bg + (size_t)64 * K + k0, Bsw + 2048);
        __syncthreads();
        bf16x8 af[4], bfr[4];
#pragma unroll
        for (int i = 0; i < 4; i++)
            af[i] = *(const bf16x8*)&As[(size_t)(wm + i * 16 + l15) * 32 + quad * 8];
#pragma unroll
        for (int j = 0; j < 4; j++)
            bfr[j] = *(const bf16x8*)&Bs[(size_t)(wn + j * 16 + l15) * 32 + quad * 8];
#pragma unroll
        for (int i = 0; i < 4; i++)
#pragma unroll
            for (int j = 0; j < 4; j++)
                acc[i][j] = mfma16(af[i], bfr[j], acc[i][j]);
        __syncthreads();
    }

    bf16*  Cb = (bf16*)Cv;
    float* Cf = (float*)Cv;
#pragma unroll
    for (int i = 0; i < 4; i++)
#pragma unroll
        for (int j = 0; j < 4; j++) {
            int col = n0 + wn + j * 16 + l15;
            float bcol = bias[col];
            if (MODE == 1) {
                int rowb = m0 + wm + i * 16 + quad * 4;      // 4 consecutive kv
                int bb = rowb >> 10, kv = rowb & 1023;       // LKV = 1024
                int h = col >> 6, d = col & 63;
                bf16x4 val = {(bf16)(acc[i][j][0] + bcol), (bf16)(acc[i][j][1] + bcol),
                              (bf16)(acc[i][j][2] + bcol), (bf16)(acc[i][j][3] + bcol)};
                *(bf16x4*)&Cb[(((size_t)(bb * NH + h) * HD) + d) * LKV + kv] = val;
            } else {
#pragma unroll
                for (int r = 0; r < 4; r++) {
                    int row = m0 + wm + i * 16 + quad * 4 + r;
                    float v = acc[i][j][r] + bcol;
                    if (MODE == 2) Cf[(size_t)row * N + col] = v;
                    else           Cb[(size_t)row * N + col] = (bf16)v;
                }
            }
        }
}

// one launch: y<64 -> Q-proj tiles, 64..79 -> K-proj, 80..95 -> V-proj
__global__ __launch_bounds__(256) void gemm_qkv(
        const bf16* xb, const bf16* Wq_t, const float* bq, bf16* qbuf,
        const bf16* yb, const bf16* Wk_t, const float* bk, bf16* kbuf,
        const bf16* Wv_t, const float* bv, bf16* vT) {
    int y = blockIdx.y;
    if (y < 64)      gemm_body<0>(xb, Wq_t, bq, qbuf, DQ, DQ,  y * 128);
    else if (y < 80) gemm_body<0>(yb, Wk_t, bk, kbuf, DQ, DKV, (y - 64) * 128);
    else             gemm_body<1>(yb, Wv_t, bv, vT,   DQ, DKV, (y - 80) * 128);
}
__global__ __launch_bounds__(256) void gemm_o(const bf16* A, const bf16* Bt,
                                              const float* bias, void* Cv) {
    gemm_body<2>(A, Bt, bias, Cv, DQ, DQ, blockIdx.y * 128);
}

// ------- RMSNorm + RoPE, one wave per row, register-resident -----------------
__global__ __launch_bounds__(256) void rmsnorm_rope3(bf16* __restrict__ qb,
                                                     bf16* __restrict__ kb,
                                                     const float* __restrict__ gq,
                                                     const float* __restrict__ gk,
                                                     const float* __restrict__ xc,
                                                     const float* __restrict__ xs,
                                                     const float* __restrict__ yc,
                                                     const float* __restrict__ ys) {
    int w = threadIdx.x >> 6, lane = threadIdx.x & 63;
    int row = blockIdx.x * 4 + w;
    bf16* t; const float *g, *cs, *sn;
    if (row < NB * LQ) {
        t = qb + (size_t)row * DQ; g = gq;
        cs = xc + (size_t)row * HD; sn = xs + (size_t)row * HD;
    } else {
        int r2 = row - NB * LQ;
        t = kb + (size_t)r2 * DQ; g = gk;
        cs = yc + (size_t)r2 * HD; sn = ys + (size_t)r2 * HD;
    }
    int c0 = lane * 16;
    bf16x8 a0 = *(const bf16x8*)&t[c0];
    bf16x8 a1 = *(const bf16x8*)&t[c0 + 8];
    float vv[16], ss = 0.f;
#pragma unroll
    for (int j = 0; j < 8; j++) { vv[j] = (float)a0[j]; vv[8 + j] = (float)a1[j]; }
#pragma unroll
    for (int j = 0; j < 16; j++) ss += vv[j] * vv[j];
#pragma unroll
    for (int off = 32; off >= 1; off >>= 1) ss += __shfl_xor(ss, off, 64);
    float rms = rsqrtf(ss * (1.0f / 1024.0f) + 1e-6f);
    float nv[16];
#pragma unroll
    for (int j = 0; j < 16; j++) nv[j] = vv[j] * rms * g[c0 + j];
    int d0 = (lane & 3) * 16;
    float sgn = (lane & 2) ? 1.f : -1.f;   // d<32 -> -partner, d>=32 -> +partner
    bf16x8 o0, o1;
#pragma unroll
    for (int j = 0; j < 16; j++) {
        float pv = __shfl_xor(nv[j], 2, 64);
        float r = nv[j] * cs[d0 + j] + sgn * pv * sn[d0 + j];
        if (j < 8) o0[j] = (bf16)r; else o1[j - 8] = (bf16)r;
    }
    *(bf16x8*)&t[c0]     = o0;
    *(bf16x8*)&t[c0 + 8] = o1;
}

// ------- flash attention v5: LDS-staged K/V, double-buffered, S^T form -------
// block = (b,h,128 q rows); wave w owns q rows {w*16..+15} and {64+w*16..+15}.
// K/V chunk (64 kv) staged cooperatively into padded LDS (+8 elem rows -> all
// frag reads/writes are 2-way conflicts = free).  One barrier per iter: reads
// hit buf[cur], staging writes hit buf[1-cur].
__global__ __launch_bounds__(256) void attn_kern(const bf16* __restrict__ q,
                                                 const bf16* __restrict__ k,
                                                 const bf16* __restrict__ vT,
                                                 bf16* __restrict__ o) {
    __shared__ bf16 Ks[2][64][72];          // [buf][kv][d]
    __shared__ bf16 Vs[2][64][72];          // [buf][d][kv]
    __shared__ bf16 pbuf[4][2][16][72];     // [wave][tile][q][kv]
    int tid = threadIdx.x, w = tid >> 6, lane = tid & 63;
    int quad = lane >> 4, l15 = lane & 15;
    int b = blockIdx.z, h = blockIdx.y, qt = blockIdx.x;
    int qrow0 = qt * 128 + w * 16;

    bf16x8 qf[2][2];
#pragma unroll
    for (int tl = 0; tl < 2; tl++) {
        size_t qb = ((size_t)(b * LQ) + qrow0 + tl * 64 + l15) * DQ + h * HD;
        qf[tl][0] = *(const bf16x8*)&q[qb + quad * 8];
        qf[tl][1] = *(const bf16x8*)&q[qb + 32 + quad * 8];
#pragma unroll
        for (int e = 0; e < 8; e++) {       // fold 1/8 scale; 2^-3 exact in bf16
            qf[tl][0][e] = (bf16)((float)qf[tl][0][e] * 0.125f);
            qf[tl][1][e] = (bf16)((float)qf[tl][1][e] * 0.125f);
        }
    }

    // staging map: thread t -> row t/4 (kv for K, d for V), 16 cols (t%4)*16
    int srow = tid >> 2, scol = (tid & 3) * 16;
    const bf16* kg = &k[((size_t)(b * LKV) + srow) * DQ + h * HD + scol];
    const bf16* vg = &vT[(((size_t)(b * NH + h) * HD) + srow) * LKV + scol];

    bf16x8 kr0 = *(const bf16x8*)kg;
    bf16x8 kr1 = *(const bf16x8*)(kg + 8);
    bf16x8 vr0 = *(const bf16x8*)vg;
    bf16x8 vr1 = *(const bf16x8*)(vg + 8);
    *(bf16x8*)&Ks[0][srow][scol]     = kr0;
    *(bf16x8*)&Ks[0][srow][scol + 8] = kr1;
    *(bf16x8*)&Vs[0][srow][scol]     = vr0;
    *(bf16x8*)&Vs[0][srow][scol + 8] = vr1;
    __syncthreads();

    f32x4 O[2][4] = {};
    float m_run[2] = {-1e30f, -1e30f}, l_run[2] = {0.f, 0.f};

    for (int i = 0; i < 16; i++) {
        int cur = i & 1;
        if (i < 15) {                        // global prefetch of chunk i+1
            size_t ko = (size_t)(i + 1) * 64 * DQ;
            kr0 = *(const bf16x8*)(kg + ko);
            kr1 = *(const bf16x8*)(kg + ko + 8);
            vr0 = *(const bf16x8*)(vg + (i + 1) * 64);
            vr1 = *(const bf16x8*)(vg + (i + 1) * 64 + 8);
        }
        // S^T = K·Q^T from LDS
        f32x4 S[2][4];
#pragma unroll
        for (int t = 0; t < 4; t++) {
            bf16x8 kf0 = *(const bf16x8*)&Ks[cur][t * 16 + l15][quad * 8];
            bf16x8 kf1 = *(const bf16x8*)&Ks[cur][t * 16 + l15][32 + quad * 8];
#pragma unroll
            for (int tl = 0; tl < 2; tl++) {
                f32x4 z = {};
                z = mfma16(kf0, qf[tl][0], z);
                S[tl][t] = mfma16(kf1, qf[tl][1], z);
            }
        }
        // online softmax per tile: scalar state per lane (q = l15)
#pragma unroll
        for (int tl = 0; tl < 2; tl++) {
            float mx = -1e30f;
#pragma unroll
            for (int t = 0; t < 4; t++)
#pragma unroll
                for (int r = 0; r < 4; r++) mx = fmaxf(mx, S[tl][t][r]);
            mx = fmaxf(mx, __shfl_xor(mx, 16, 64));
            mx = fmaxf(mx, __shfl_xor(mx, 32, 64));
            float mn = fmaxf(m_run[tl], mx);
            float alpha = __expf(m_run[tl] - mn);
            m_run[tl] = mn;
            float rs = 0.f;
#pragma unroll
            for (int t = 0; t < 4; t++) {
                float p0 = __expf(S[tl][t][0] - mn), p1 = __expf(S[tl][t][1] - mn);
                float p2 = __expf(S[tl][t][2] - mn), p3 = __expf(S[tl][t][3] - mn);
                rs += (p0 + p1) + (p2 + p3);
                bf16x4 pb4 = {(bf16)p0, (bf16)p1, (bf16)p2, (bf16)p3};
                *(bf16x4*)&pbuf[w][tl][l15][t * 16 + quad * 4] = pb4;
            }
            rs += __shfl_xor(rs, 16, 64);
            rs += __shfl_xor(rs, 32, 64);
            l_run[tl] = l_run[tl] * alpha + rs;
#pragma unroll
            for (int td = 0; td < 4; td++)
#pragma unroll
                for (int r = 0; r < 4; r++) O[tl][td][r] *= alpha;
        }
        asm volatile("s_waitcnt lgkmcnt(0)" ::: "memory");  // wave-local RAW on pbuf
        // PV: O^T += V^T·P^T (K=32), V from LDS, P read back in B-layout
#pragma unroll
        for (int tl = 0; tl < 2; tl++) {
            bf16x8 pf0 = *(const bf16x8*)&pbuf[w][tl][l15][quad * 8];
            bf16x8 pf1 = *(const bf16x8*)&pbuf[w][tl][l15][32 + quad * 8];
#pragma unroll
            for (int td = 0; td < 4; td++) {
                bf16x8 vf0 = *(const bf16x8*)&Vs[cur][td * 16 + l15][quad * 8];
                bf16x8 vf1 = *(const bf16x8*)&Vs[cur][td * 16 + l15][32 + quad * 8];
                O[tl][td] = mfma16(vf0, pf0, O[tl][td]);
                O[tl][td] = mfma16(vf1, pf1, O[tl][td]);
            }
        }
        // stage chunk i+1 into the other buffer, then single barrier
        if (i < 15) {
            int nxt = 1 - cur;
            *(bf16x8*)&Ks[nxt][srow][scol]     = kr0;
            *(bf16x8*)&Ks[nxt][srow][scol + 8] = kr1;
            *(bf16x8*)&Vs[nxt][srow][scol]     = vr0;
            *(bf16x8*)&Vs[nxt][srow][scol + 8] = vr1;
            __syncthreads();
        }
    }

#pragma unroll
    for (int tl = 0; tl < 2; tl++) {
        float inv = 1.0f / l_run[tl];
        size_t orow = ((size_t)(b * LQ) + qrow0 + tl * 64 + l15) * DQ + h * HD;
#pragma unroll
        for (int td = 0; td < 4; td++) {
            bf16x4 ov = {(bf16)(O[tl][td][0] * inv), (bf16)(O[tl][td][1] * inv),
                         (bf16)(O[tl][td][2] * inv), (bf16)(O[tl][td][3] * inv)};
            *(bf16x4*)&o[orow + td * 16 + quad * 4] = ov;
        }
    }
}

// ---------------------------------------------------------------------------
extern "C" void kernel_launch(void* const* d_in, const int* in_sizes, int n_in,
                              void* d_out, int out_size, void* d_ws, size_t ws_size,
                              hipStream_t stream) {
    const float* x     = (const float*)d_in[0];
    const float* y     = (const float*)d_in[1];
    const float* x_cos = (const float*)d_in[2];
    const float* x_sin = (const float*)d_in[3];
    const float* y_cos = (const float*)d_in[4];
    const float* y_sin = (const float*)d_in[5];
    const float* Wq    = (const float*)d_in[6];
    const float* bq    = (const float*)d_in[7];
    const float* Wk    = (const float*)d_in[8];
    const float* bk    = (const float*)d_in[9];
    const float* Wv    = (const float*)d_in[10];
    const float* bv    = (const float*)d_in[11];
    const float* Wo    = (const float*)d_in[12];
    const float* bo    = (const float*)d_in[13];
    const float* gq    = (const float*)d_in[14];
    const float* gk    = (const float*)d_in[15];

    char* ws = (char*)d_ws;
    bf16* Wq_t = (bf16*)ws;  ws += (size_t)DQ * DQ * 2;
    bf16* Wk_t = (bf16*)ws;  ws += (size_t)DQ * DKV * 2;
    bf16* Wv_t = (bf16*)ws;  ws += (size_t)DQ * DKV * 2;
    bf16* Wo_t = (bf16*)ws;  ws += (size_t)DQ * DQ * 2;
    bf16* qbuf = (bf16*)ws;  ws += (size_t)NB * LQ * DQ * 2;
    bf16* kbuf = (bf16*)ws;  ws += (size_t)NB * LKV * DQ * 2;
    bf16* vT   = (bf16*)ws;  ws += (size_t)NB * NH * HD * LKV * 2;
    bf16* aout = (bf16*)ws;  ws += (size_t)NB * LQ * DQ * 2;
    bf16* yb   = (bf16*)ws;  ws += (size_t)NB * LKV * DKV * 2;
    bf16* xb   = aout;  // alias: xb dead (last read = Q-proj) before attn writes aout

    int nx8 = NB * LQ * DQ / 8, ny8 = NB * LKV * DKV / 8;
    prep<<<dim3(32, 32, 5), dim3(32, 8), 0, stream>>>(
        Wq, Wk, Wv, Wo, Wq_t, Wk_t, Wv_t, Wo_t,
        x, y, xb, yb, nx8, nx8 + ny8);

    gemm_qkv<<<dim3(8, 96), 256, 0, stream>>>(
        xb, Wq_t, bq, qbuf, yb, Wk_t, bk, kbuf, Wv_t, bv, vT);

    rmsnorm_rope3<<<NB * (LQ + LKV) / 4, 256, 0, stream>>>(
        qbuf, kbuf, gq, gk, x_cos, x_sin, y_cos, y_sin);

    attn_kern<<<dim3(LQ / 128, NH, NB), 256, 0, stream>>>(qbuf, kbuf, vT, aout);

    gemm_o<<<dim3(DQ / 128, NB * LQ / 128), 256, 0, stream>>>(aout, Wo_t, bo, d_out);
}